// Round 15
// baseline (335.160 us; speedup 1.0000x reference)
//
#include <hip/hip_runtime.h>
#include <hip/hip_bf16.h>

// GRU policy: B=2048, T=512, V=4, E=64, H=128.
// R14 = R13 (best: 276us kernel) + gi-table computation FUSED into gru_kernel
// setup (drops the separate dispatch + inter-kernel dependency, ~6-10us of
// the dur-vs-kernel gap). Each block redundantly computes the 6KB table:
// 3 x dot-64 per thread (~192 FMA); W_ih is L2-resident after block 0.
// Kernel structure unchanged: 12 MFMA/wave-step, packed-fp32 (v_pk_*) fused
// gate tail, 20 trans, 1 barrier/step, 128 blocks (structural: B/16 groups).
// Step model (R6-R13 ledger): 1292 cyc = VALU 667 + MFMA 395 + LDS/latency,
// serialized by the barrier join; antiphase/2-group variants floor >= this
// by arithmetic (VALU per group-step is CU-invariant).

#define B_  2048
#define T_  512
#define V_  4
#define E_  64
#define H_  128
#define G3  384
#define SH  136            // h row stride (bf16 elems)

#define LOG2E 1.4426950408889634f

typedef __attribute__((ext_vector_type(8))) short  short8;   // 8 bf16
typedef __attribute__((ext_vector_type(4))) float  float4v;
typedef __attribute__((ext_vector_type(2))) float  f32x2;    // -> v_pk_* f32
typedef unsigned long long ull;

__device__ __forceinline__ short bf16s(float f) {            // RNE scalar (setup only)
  union { float ff; unsigned int u; } c; c.ff = f;
  return (short)((c.u + 0x7fffu + ((c.u >> 16) & 1u)) >> 16);
}

#define MFMA16(A, B, C) __builtin_amdgcn_mfma_f32_16x16x32_bf16((A), (B), (C), 0, 0, 0)

__global__ __launch_bounds__(512) void gru_kernel(
    const int* __restrict__ x, const float* __restrict__ emb,
    const float* __restrict__ W_ih, const float* __restrict__ b_ih,
    const float* __restrict__ W_hh, const float* __restrict__ b_hh,
    const float* __restrict__ W_fc, const float* __restrict__ b_fc,
    float* __restrict__ out) {
  __shared__ __align__(16) short hbuf[2][16 * SH];          // bf16 h, double-buffered
  __shared__ __align__(16) unsigned char xs[(T_ + 2) * 16]; // tokens [t][row], 2 pad rows
  __shared__ __align__(16) float tabS[V_ * G3];             // gi table (pre-scaled)
  __shared__ __align__(16) float hf[16 * H_];               // epilogue fp32 h

  const int tid  = threadIdx.x;
  const int w    = tid >> 6;        // wave 0..7
  const int lane = tid & 63;
  const int m    = lane & 15;       // batch row (B/C col) and A gate-row
  const int q    = lane >> 4;       // quad
  const int g0   = blockIdx.x * 16;

  // ---- stage x -> xs[t][r] bytes; zero the 2 pad rows ----
  for (int i = tid; i < 16 * T_; i += 512) {
    int r = i >> 9;                 // 0..15
    int t = i & (T_ - 1);
    xs[t * 16 + r] = (unsigned char)(x[(g0 + r) * T_ + t] & 3);
  }
  if (tid < 32) xs[T_ * 16 + tid] = 0;

  // ---- compute gi table in-block (fused; was a separate kernel) ----
  // tabS[v*G3+g] = scale_g * (b_ih[g] + sum_e W_ih[g,e]*emb[v,e] (+b_hh[g], g<2H))
  // scale_g = -log2e for r,z rows; +2*log2e for n rows (b_hh_n NOT folded).
  for (int i = tid; i < V_ * G3; i += 512) {
    int v = i / G3;
    int g = i - v * G3;
    float acc = b_ih[g];
    if (g < 2 * H_) acc += b_hh[g];
    const float* wr = W_ih + g * E_;
    const float* er = emb + v * E_;
#pragma unroll 8
    for (int e = 0; e < E_; ++e) acc += wr[e] * er[e];
    tabS[i] = acc * ((g < 2 * H_) ? -LOG2E : 2.f * LOG2E);
  }

  // ---- h0 = 0 ----
  for (int i = tid; i < 16 * SH; i += 512) hbuf[0][i] = 0;

  // ---- persistent A-fragments: W_hh tiles (pre-scaled), A[g=m][k=q*8+j] ----
  short8 wA[3][4];
#pragma unroll
  for (int s = 0; s < 3; ++s) {
    const float sc = (s < 2) ? -LOG2E : 2.f * LOG2E;
    const float* wrow = W_hh + (s * H_ + w * 16 + m) * H_;
#pragma unroll
    for (int ks = 0; ks < 4; ++ks) {
      const float* p = wrow + ks * 32 + q * 8;
      short8 f;
#pragma unroll
      for (int jj = 0; jj < 8; ++jj) f[jj] = bf16s(p[jj] * sc);
      wA[s][ks] = f;
    }
  }

  const int c0 = w * 16 + q * 4;    // this lane's h-col base
  float4v bhnC;                     // a2 chain C-init: b_hh_n * 2log2e
  {
    const float* p = b_hh + 2 * H_ + c0;
#pragma unroll
    for (int i = 0; i < 4; ++i) bhnC[i] = p[i] * 2.f * LOG2E;
  }
  f32x2 hA = {0.f, 0.f}, hB = {0.f, 0.f};   // h for rows (0,1) and (2,3) packed

  __syncthreads();

  // ---- prologue: gi(0) into set A; token byte of t=1 ----
  float4v gAR, gAZ, gAN, gBR, gBZ, gBN;
  int vb;
  {
    int v0 = xs[m] & 3;
    const float* tb = &tabS[v0 * G3 + c0];
    gAR = *(const float4v*)(tb);
    gAZ = *(const float4v*)(tb + H_);
    gAN = *(const float4v*)(tb + 2 * H_);
    vb  = xs[16 + m];
  }

  const f32x2 one2 = {1.f, 1.f};

  auto step = [&](int FROM, int TO, int t,
                  float4v& guR, float4v& guZ, float4v& guN,     // gi used this step
                  float4v& glR, float4v& glZ, float4v& glN) {   // gi loaded for next
    // h fragments — the ONLY LDS reads that gate this step's MFMAs
    const short* rbp = &hbuf[FROM][m * SH + q * 8];
    short8 h0 = *(const short8*)(rbp);
    short8 h1 = *(const short8*)(rbp + 32);
    short8 h2 = *(const short8*)(rbp + 64);
    short8 h3 = *(const short8*)(rbp + 96);

    // ---- all 12 MFMAs up front; a0 (r) leads, a2, a1 (z) last ----
    float4v a0 = MFMA16(wA[0][0], h0, guR);
    a0 = MFMA16(wA[0][1], h1, a0);
    a0 = MFMA16(wA[0][2], h2, a0);
    a0 = MFMA16(wA[0][3], h3, a0);
    float4v a2 = MFMA16(wA[2][0], h0, bhnC);
    a2 = MFMA16(wA[2][1], h1, a2);
    a2 = MFMA16(wA[2][2], h2, a2);
    a2 = MFMA16(wA[2][3], h3, a2);
    float4v a1 = MFMA16(wA[1][0], h0, guZ);
    a1 = MFMA16(wA[1][1], h1, a1);
    a1 = MFMA16(wA[1][2], h2, a1);
    a1 = MFMA16(wA[1][3], h3, a1);

    // ---- r = rcp(1+Er): scalar trans, under the queue drain ----
    float r0 = __builtin_amdgcn_rcpf(1.f + __builtin_amdgcn_exp2f(a0[0]));
    float r1 = __builtin_amdgcn_rcpf(1.f + __builtin_amdgcn_exp2f(a0[1]));
    float r2 = __builtin_amdgcn_rcpf(1.f + __builtin_amdgcn_exp2f(a0[2]));
    float r3 = __builtin_amdgcn_rcpf(1.f + __builtin_amdgcn_exp2f(a0[3]));

    // ---- next-step gi preloads into the other register set ----
    int vb2 = xs[(t + 2) * 16 + m];
    const float* tbn = &tabS[(vb & 3) * G3 + c0];
    glR = *(const float4v*)(tbn);
    glZ = *(const float4v*)(tbn + H_);
    glN = *(const float4v*)(tbn + 2 * H_);
    vb = vb2;

    // ---- packed fused tail: h' = [e2n(Ez+h)+(h-Ez)] * rcp[(e2n+1)(1+Ez)] ----
    f32x2 rA = {r0, r1},           rB = {r2, r3};
    f32x2 a2A = {a2[0], a2[1]},    a2B = {a2[2], a2[3]};
    f32x2 gnA = {guN[0], guN[1]},  gnB = {guN[2], guN[3]};
    f32x2 npA = rA * a2A + gnA;                    // v_pk_fma_f32
    f32x2 npB = rB * a2B + gnB;
    f32x2 eA = {__builtin_amdgcn_exp2f(npA.x), __builtin_amdgcn_exp2f(npA.y)};
    f32x2 eB = {__builtin_amdgcn_exp2f(npB.x), __builtin_amdgcn_exp2f(npB.y)};
    f32x2 EzA = {__builtin_amdgcn_exp2f(a1[0]), __builtin_amdgcn_exp2f(a1[1])};
    f32x2 EzB = {__builtin_amdgcn_exp2f(a1[2]), __builtin_amdgcn_exp2f(a1[3])};
    f32x2 numA = eA * (EzA + hA) + (hA - EzA);     // pk_add, pk_fma, pk_add(neg)
    f32x2 numB = eB * (EzB + hB) + (hB - EzB);
    f32x2 denA = (eA + one2) * (one2 + EzA);       // pk_add x2, pk_mul
    f32x2 denB = (eB + one2) * (one2 + EzB);
    f32x2 rcA = {__builtin_amdgcn_rcpf(denA.x), __builtin_amdgcn_rcpf(denA.y)};
    f32x2 rcB = {__builtin_amdgcn_rcpf(denB.x), __builtin_amdgcn_rcpf(denB.y)};
    hA = numA * rcA;                               // pk_mul
    hB = numB * rcB;
    union { float ff; unsigned int u; } c0u, c1u, c2u, c3u;
    c0u.ff = hA.x; c1u.ff = hA.y; c2u.ff = hB.x; c3u.ff = hB.y;
    unsigned int pk0 = __builtin_amdgcn_perm(c1u.u + 0x8000u, c0u.u + 0x8000u, 0x07060302u);
    unsigned int pk1 = __builtin_amdgcn_perm(c3u.u + 0x8000u, c2u.u + 0x8000u, 0x07060302u);
    *(ull*)(&hbuf[TO][m * SH + c0]) = ((ull)pk1 << 32) | pk0;
    __syncthreads();
  };

  for (int t = 0; t < T_; t += 2) {
    step(0, 1, t,     gAR, gAZ, gAN, gBR, gBZ, gBN);
    step(1, 0, t + 1, gBR, gBZ, gBN, gAR, gAZ, gAN);
  }

  // ---- epilogue: logits = hT @ W_fc^T + b_fc ----
  hf[m * H_ + c0 + 0] = hA.x;
  hf[m * H_ + c0 + 1] = hA.y;
  hf[m * H_ + c0 + 2] = hB.x;
  hf[m * H_ + c0 + 3] = hB.y;
  __syncthreads();

  if (tid < 64) {
    int row = tid >> 2, vo = tid & 3;
    float s = b_fc[vo];
    const float* wv = W_fc + vo * H_;
    const float* hr = &hf[row * H_];
#pragma unroll 4
    for (int k = 0; k < H_; k += 4)
      s += hr[k] * wv[k] + hr[k + 1] * wv[k + 1]
         + hr[k + 2] * wv[k + 2] + hr[k + 3] * wv[k + 3];
    out[(g0 + row) * V_ + vo] = s;
  }
}

extern "C" void kernel_launch(void* const* d_in, const int* in_sizes, int n_in,
                              void* d_out, int out_size, void* d_ws, size_t ws_size,
                              hipStream_t stream) {
  const int*   x    = (const int*)d_in[0];
  const float* emb  = (const float*)d_in[1];
  const float* W_ih = (const float*)d_in[2];
  const float* W_hh = (const float*)d_in[3];
  const float* b_ih = (const float*)d_in[4];
  const float* b_hh = (const float*)d_in[5];
  const float* W_fc = (const float*)d_in[6];
  const float* b_fc = (const float*)d_in[7];
  float* out = (float*)d_out;

  gru_kernel<<<B_ / 16, 512, 0, stream>>>(x, emb, W_ih, b_ih, W_hh, b_hh,
                                          W_fc, b_fc, out);
}

// Round 16
// 320.998 us; speedup vs baseline: 1.0441x; 1.0441x over previous
//
#include <hip/hip_runtime.h>
#include <hip/hip_bf16.h>

// GRU policy: B=2048, T=512, V=4, E=64, H=128.
// R15 = R13 reverted (measured best: 276us kernel / 321us dur). R14's fused
// table compute regressed (+17us kernel: 128x redundant latency-bound scalar
// dot-64s; FETCH 2899->3272 KB) — the dur-kernel gap (~43us) is harness
// overhead, not the second dispatch.
// FINAL STRUCTURE: V=4 -> input projections collapse to a [4][384] table
// (separate tiny kernel); recurrence = 512 barrier-locked steps of
// [16x128]@[128x384] bf16 MFMA per block; 12 MFMA/wave-step; fused gate
// algebra (one rcp for z+tanh), exp2 pre-scaling, packed-fp32 (v_pk_*) tail;
// gi preloaded 1 step ahead; h round-trips LDS as bf16, 1 barrier/step.
// Step model (R6-R14 ledger): ~1294 cyc = sum of pipes (MFMA 395 + VALU
// ~600 + LDS 230 + join), serialized; 6 overlap mechanisms tried, 0 worked —
// barrier-lockstep + in-order issue + compiler MFMA clustering make phase
// tiling unreachable at source level on this HW/compiler.

#define B_  2048
#define T_  512
#define V_  4
#define E_  64
#define H_  128
#define G3  384
#define SH  136            // h row stride (bf16 elems)

#define LOG2E 1.4426950408889634f

typedef __attribute__((ext_vector_type(8))) short  short8;   // 8 bf16
typedef __attribute__((ext_vector_type(4))) float  float4v;
typedef __attribute__((ext_vector_type(2))) float  f32x2;    // -> v_pk_* f32
typedef unsigned long long ull;

__device__ __forceinline__ short bf16s(float f) {            // RNE scalar (setup only)
  union { float ff; unsigned int u; } c; c.ff = f;
  return (short)((c.u + 0x7fffu + ((c.u >> 16) & 1u)) >> 16);
}

// table[v][g] = scale_g * (b_ih[g] + sum_e W_ih[g,e]*emb[v,e] (+ b_hh[g] for g<2H))
// scale_g = -log2e for r,z rows; +2*log2e for n rows (b_hh_n NOT folded).
__global__ void gi_table_kernel(const float* __restrict__ emb,
                                const float* __restrict__ W_ih,
                                const float* __restrict__ b_ih,
                                const float* __restrict__ b_hh,
                                float* __restrict__ table) {
  int gid = blockIdx.x * blockDim.x + threadIdx.x;
  if (gid >= V_ * G3) return;
  int v = gid / G3;
  int g = gid - v * G3;
  float acc = b_ih[g];
  if (g < 2 * H_) acc += b_hh[g];
  const float* wr = W_ih + g * E_;
  const float* er = emb + v * E_;
#pragma unroll 8
  for (int e = 0; e < E_; ++e) acc += wr[e] * er[e];
  table[gid] = acc * ((g < 2 * H_) ? -LOG2E : 2.f * LOG2E);
}

#define MFMA16(A, B, C) __builtin_amdgcn_mfma_f32_16x16x32_bf16((A), (B), (C), 0, 0, 0)

__global__ __launch_bounds__(512) void gru_kernel(
    const int* __restrict__ x, const float* __restrict__ W_hh,
    const float* __restrict__ b_hh, const float* __restrict__ W_fc,
    const float* __restrict__ b_fc, const float* __restrict__ table,
    float* __restrict__ out) {
  __shared__ __align__(16) short hbuf[2][16 * SH];          // bf16 h, double-buffered
  __shared__ __align__(16) unsigned char xs[(T_ + 2) * 16]; // tokens [t][row], 2 pad rows
  __shared__ __align__(16) float tabS[V_ * G3];             // gi table (pre-scaled)
  __shared__ __align__(16) float hf[16 * H_];               // epilogue fp32 h

  const int tid  = threadIdx.x;
  const int w    = tid >> 6;        // wave 0..7
  const int lane = tid & 63;
  const int m    = lane & 15;       // batch row (B/C col) and A gate-row
  const int q    = lane >> 4;       // quad
  const int g0   = blockIdx.x * 16;

  // ---- stage x -> xs[t][r] bytes; zero the 2 pad rows ----
  for (int i = tid; i < 16 * T_; i += 512) {
    int r = i >> 9;                 // 0..15
    int t = i & (T_ - 1);
    xs[t * 16 + r] = (unsigned char)(x[(g0 + r) * T_ + t] & 3);
  }
  if (tid < 32) xs[T_ * 16 + tid] = 0;
  // ---- stage gi table to LDS ----
  for (int i = tid; i < V_ * G3; i += 512) tabS[i] = table[i];
  // ---- h0 = 0 ----
  for (int i = tid; i < 16 * SH; i += 512) hbuf[0][i] = 0;

  // ---- persistent A-fragments: W_hh tiles (pre-scaled), A[g=m][k=q*8+j] ----
  short8 wA[3][4];
#pragma unroll
  for (int s = 0; s < 3; ++s) {
    const float sc = (s < 2) ? -LOG2E : 2.f * LOG2E;
    const float* wrow = W_hh + (s * H_ + w * 16 + m) * H_;
#pragma unroll
    for (int ks = 0; ks < 4; ++ks) {
      const float* p = wrow + ks * 32 + q * 8;
      short8 f;
#pragma unroll
      for (int jj = 0; jj < 8; ++jj) f[jj] = bf16s(p[jj] * sc);
      wA[s][ks] = f;
    }
  }

  const int c0 = w * 16 + q * 4;    // this lane's h-col base
  float4v bhnC;                     // a2 chain C-init: b_hh_n * 2log2e
  {
    const float* p = b_hh + 2 * H_ + c0;
#pragma unroll
    for (int i = 0; i < 4; ++i) bhnC[i] = p[i] * 2.f * LOG2E;
  }
  f32x2 hA = {0.f, 0.f}, hB = {0.f, 0.f};   // h for rows (0,1) and (2,3) packed

  __syncthreads();

  // ---- prologue: gi(0) into set A; token byte of t=1 ----
  float4v gAR, gAZ, gAN, gBR, gBZ, gBN;
  int vb;
  {
    int v0 = xs[m] & 3;
    const float* tb = &tabS[v0 * G3 + c0];
    gAR = *(const float4v*)(tb);
    gAZ = *(const float4v*)(tb + H_);
    gAN = *(const float4v*)(tb + 2 * H_);
    vb  = xs[16 + m];
  }

  const f32x2 one2 = {1.f, 1.f};

  auto step = [&](int FROM, int TO, int t,
                  float4v& guR, float4v& guZ, float4v& guN,     // gi used this step
                  float4v& glR, float4v& glZ, float4v& glN) {   // gi loaded for next
    // h fragments — the ONLY LDS reads that gate this step's MFMAs
    const short* rbp = &hbuf[FROM][m * SH + q * 8];
    short8 h0 = *(const short8*)(rbp);
    short8 h1 = *(const short8*)(rbp + 32);
    short8 h2 = *(const short8*)(rbp + 64);
    short8 h3 = *(const short8*)(rbp + 96);

    // ---- all 12 MFMAs up front; a0 (r) leads, a2, a1 (z) last ----
    float4v a0 = MFMA16(wA[0][0], h0, guR);
    a0 = MFMA16(wA[0][1], h1, a0);
    a0 = MFMA16(wA[0][2], h2, a0);
    a0 = MFMA16(wA[0][3], h3, a0);
    float4v a2 = MFMA16(wA[2][0], h0, bhnC);
    a2 = MFMA16(wA[2][1], h1, a2);
    a2 = MFMA16(wA[2][2], h2, a2);
    a2 = MFMA16(wA[2][3], h3, a2);
    float4v a1 = MFMA16(wA[1][0], h0, guZ);
    a1 = MFMA16(wA[1][1], h1, a1);
    a1 = MFMA16(wA[1][2], h2, a1);
    a1 = MFMA16(wA[1][3], h3, a1);

    // ---- r = rcp(1+Er): scalar trans, under the queue drain ----
    float r0 = __builtin_amdgcn_rcpf(1.f + __builtin_amdgcn_exp2f(a0[0]));
    float r1 = __builtin_amdgcn_rcpf(1.f + __builtin_amdgcn_exp2f(a0[1]));
    float r2 = __builtin_amdgcn_rcpf(1.f + __builtin_amdgcn_exp2f(a0[2]));
    float r3 = __builtin_amdgcn_rcpf(1.f + __builtin_amdgcn_exp2f(a0[3]));

    // ---- next-step gi preloads into the other register set ----
    int vb2 = xs[(t + 2) * 16 + m];
    const float* tbn = &tabS[(vb & 3) * G3 + c0];
    glR = *(const float4v*)(tbn);
    glZ = *(const float4v*)(tbn + H_);
    glN = *(const float4v*)(tbn + 2 * H_);
    vb = vb2;

    // ---- packed fused tail: h' = [e2n(Ez+h)+(h-Ez)] * rcp[(e2n+1)(1+Ez)] ----
    f32x2 rA = {r0, r1},           rB = {r2, r3};
    f32x2 a2A = {a2[0], a2[1]},    a2B = {a2[2], a2[3]};
    f32x2 gnA = {guN[0], guN[1]},  gnB = {guN[2], guN[3]};
    f32x2 npA = rA * a2A + gnA;                    // v_pk_fma_f32
    f32x2 npB = rB * a2B + gnB;
    f32x2 eA = {__builtin_amdgcn_exp2f(npA.x), __builtin_amdgcn_exp2f(npA.y)};
    f32x2 eB = {__builtin_amdgcn_exp2f(npB.x), __builtin_amdgcn_exp2f(npB.y)};
    f32x2 EzA = {__builtin_amdgcn_exp2f(a1[0]), __builtin_amdgcn_exp2f(a1[1])};
    f32x2 EzB = {__builtin_amdgcn_exp2f(a1[2]), __builtin_amdgcn_exp2f(a1[3])};
    f32x2 numA = eA * (EzA + hA) + (hA - EzA);     // pk_add, pk_fma, pk_add(neg)
    f32x2 numB = eB * (EzB + hB) + (hB - EzB);
    f32x2 denA = (eA + one2) * (one2 + EzA);       // pk_add x2, pk_mul
    f32x2 denB = (eB + one2) * (one2 + EzB);
    f32x2 rcA = {__builtin_amdgcn_rcpf(denA.x), __builtin_amdgcn_rcpf(denA.y)};
    f32x2 rcB = {__builtin_amdgcn_rcpf(denB.x), __builtin_amdgcn_rcpf(denB.y)};
    hA = numA * rcA;                               // pk_mul
    hB = numB * rcB;
    union { float ff; unsigned int u; } c0u, c1u, c2u, c3u;
    c0u.ff = hA.x; c1u.ff = hA.y; c2u.ff = hB.x; c3u.ff = hB.y;
    unsigned int pk0 = __builtin_amdgcn_perm(c1u.u + 0x8000u, c0u.u + 0x8000u, 0x07060302u);
    unsigned int pk1 = __builtin_amdgcn_perm(c3u.u + 0x8000u, c2u.u + 0x8000u, 0x07060302u);
    *(ull*)(&hbuf[TO][m * SH + c0]) = ((ull)pk1 << 32) | pk0;
    __syncthreads();
  };

  for (int t = 0; t < T_; t += 2) {
    step(0, 1, t,     gAR, gAZ, gAN, gBR, gBZ, gBN);
    step(1, 0, t + 1, gBR, gBZ, gBN, gAR, gAZ, gAN);
  }

  // ---- epilogue: logits = hT @ W_fc^T + b_fc ----
  hf[m * H_ + c0 + 0] = hA.x;
  hf[m * H_ + c0 + 1] = hA.y;
  hf[m * H_ + c0 + 2] = hB.x;
  hf[m * H_ + c0 + 3] = hB.y;
  __syncthreads();

  if (tid < 64) {
    int row = tid >> 2, vo = tid & 3;
    float s = b_fc[vo];
    const float* wv = W_fc + vo * H_;
    const float* hr = &hf[row * H_];
#pragma unroll 4
    for (int k = 0; k < H_; k += 4)
      s += hr[k] * wv[k] + hr[k + 1] * wv[k + 1]
         + hr[k + 2] * wv[k + 2] + hr[k + 3] * wv[k + 3];
    out[(g0 + row) * V_ + vo] = s;
  }
}

extern "C" void kernel_launch(void* const* d_in, const int* in_sizes, int n_in,
                              void* d_out, int out_size, void* d_ws, size_t ws_size,
                              hipStream_t stream) {
  const int*   x    = (const int*)d_in[0];
  const float* emb  = (const float*)d_in[1];
  const float* W_ih = (const float*)d_in[2];
  const float* W_hh = (const float*)d_in[3];
  const float* b_ih = (const float*)d_in[4];
  const float* b_hh = (const float*)d_in[5];
  const float* W_fc = (const float*)d_in[6];
  const float* b_fc = (const float*)d_in[7];
  float* out   = (float*)d_out;
  float* table = (float*)d_ws;     // 4*384 fp32 = 6 KB

  gi_table_kernel<<<(V_ * G3 + 255) / 256, 256, 0, stream>>>(emb, W_ih, b_ih, b_hh, table);
  gru_kernel<<<B_ / 16, 512, 0, stream>>>(x, W_hh, b_hh, W_fc, b_fc, table, out);
}